// Round 6
// baseline (734.603 us; speedup 1.0000x reference)
//
#include <hip/hip_runtime.h>
#include <hip/hip_bf16.h>
#include <math.h>

#define HWN 4096      // 64*64
#define DCH 256
#define EPSV 1e-5f

typedef unsigned short u16;
typedef __attribute__((ext_vector_type(8))) short short8b;   // 8 bf16 payload
typedef __attribute__((ext_vector_type(4))) float fx4;
typedef __attribute__((ext_vector_type(8))) unsigned short u16x8;

static __device__ inline u16 f2bf(float f) {
  __hip_bfloat16 h = __float2bfloat16(f);
  return *reinterpret_cast<u16*>(&h);
}
static __device__ inline float bf2f(u16 u) {
  unsigned int v = ((unsigned int)u) << 16;
  return __uint_as_float(v);
}

// ---------------- batched NCHW f32 -> CHWc bf16 (3 branches x 2 batch) ----------------
__global__ __launch_bounds__(256) void t_chwc3_k(const float* __restrict__ i0p,
    const float* __restrict__ i1p, const float* __restrict__ i2p,
    u16* __restrict__ out) {
  __shared__ float tl[32][257];
  const int p0 = blockIdx.x * 256, cic = blockIdx.y;
  const int z = blockIdx.z;             // br*2 + b
  const int br = z >> 1, b = z & 1;
  const float* in = (br == 0) ? i0p : ((br == 1) ? i1p : i2p);
  const int t = threadIdx.x;
  const float* ip = in + ((size_t)(b * 512 + cic * 32)) * HWN + p0;
#pragma unroll
  for (int r = 0; r < 32; ++r) tl[r][t] = ip[(size_t)r * HWN + t];
  __syncthreads();
  u16* op = out + ((size_t)((z * 16 + cic)) * HWN + p0 + t) * 32;
#pragma unroll
  for (int g = 0; g < 4; ++g) {
    u16x8 o;
#pragma unroll
    for (int j = 0; j < 8; ++j) o[j] = f2bf(tl[g * 8 + j][t]);
    *reinterpret_cast<u16x8*>(op + g * 8) = o;
  }
}

// ---------------- weights OIHW f32 -> fragment-packed bf16 ----------------
template<int CIN, int COUT>
__global__ __launch_bounds__(256) void wpack_k(const float* __restrict__ w0,
    const float* __restrict__ w1, const float* __restrict__ w2,
    u16* __restrict__ wp) {
  constexpr int NCIC = CIN / 32, NCOG = COUT / 16;
  const int br = blockIdx.y;
  const float* w = (br == 0) ? w0 : ((br == 1) ? w1 : w2);
  u16* wpb = wp + (size_t)br * 9 * NCIC * NCOG * 512;
  const int cog = blockIdx.x % NCOG, cic = blockIdx.x / NCOG;
  __shared__ float ws_[16 * 32 * 9];    // 18 KB
  const int t = threadIdx.x;
  const float* src = w + ((size_t)(cog * 16) * CIN + cic * 32) * 9;
  for (int i = t; i < 4608; i += 256) {
    int co = i / 288, r = i % 288;
    ws_[i] = src[(size_t)co * CIN * 9 + r];
  }
  __syncthreads();
  const size_t tapstride = (size_t)NCIC * NCOG * 512;
  const size_t base = ((size_t)cic * NCOG + cog) * 512;
#pragma unroll
  for (int tap = 0; tap < 9; ++tap) {
#pragma unroll
    for (int e0 = 0; e0 < 512; e0 += 256) {
      int e = e0 + t;
      int kg = e >> 7, m = (e >> 3) & 15, j = e & 7;
      wpb[tap * tapstride + base + e] = f2bf(ws_[m * 288 + (kg * 8 + j) * 9 + tap]);
    }
  }
}

// ---------------- split-K direct MFMA conv 3x3 pad 1 (straight-line body) -------------
template<int CIN, int COUT, int SPLIT, bool BF16OUT>
__global__ __launch_bounds__(256, 4) void convsp_k(
    const u16* __restrict__ xt, const u16* __restrict__ wp,
    void* __restrict__ outv) {
  constexpr int NCIC = CIN / 32;
  constexpr int NCO = COUT / 64;
  constexpr int CICPS = NCIC / SPLIT;
  constexpr size_t OUTEL = (size_t)2 * COUT * HWN;
  const int br = blockIdx.y;
  xt += (size_t)br * 2 * NCIC * HWN * 32;
  wp += (size_t)br * 9 * NCIC * (COUT / 16) * 512;

  int g = blockIdx.x;
  const int cpx = (int)gridDim.x >> 3;
  g = (g & 7) * cpx + (g >> 3);
  const int s = g / (32 * NCO);
  const int rem = g % (32 * NCO);
  const int rt = rem / NCO;
  const int cob = (rem % NCO) * 64;

  const int wv = threadIdx.x >> 6, lane = threadIdx.x & 63;
  const int row = rt * 4 + wv;
  const int b = row >> 6, h = row & 63;
  const int m = lane & 15, kg = lane >> 4;

  fx4 acc[4][4];
#pragma unroll
  for (int i = 0; i < 4; ++i)
#pragma unroll
    for (int jn = 0; jn < 4; ++jn) acc[i][jn] = (fx4){0.f, 0.f, 0.f, 0.f};

  const short8b zero8 = (short8b){0, 0, 0, 0, 0, 0, 0, 0};

#pragma unroll 1
  for (int cic = s * CICPS; cic < (s + 1) * CICPS; ++cic) {
    const u16* xbase = xt + ((size_t)(b * NCIC + cic)) * HWN * 32;
#pragma unroll
    for (int ty = 0; ty < 3; ++ty) {
      const int hh = h + ty - 1;
      const bool rok = ((unsigned)hh < 64u);
      const u16* rowp = xbase + (size_t)(rok ? hh : h) * 2048 + kg * 8;
#pragma unroll
      for (int tx = 0; tx < 3; ++tx) {
        short8b a[4];
#pragma unroll
        for (int mt = 0; mt < 4; ++mt) {
          int wi = mt * 16 + m + tx - 1;
          bool wok = ((unsigned)wi < 64u);
          int wc = wok ? wi : 0;
          short8b v = *reinterpret_cast<const short8b*>(rowp + wc * 32);
          a[mt] = (rok && wok) ? v : zero8;
        }
        const int tap = ty * 3 + tx;
        const u16* wt = wp + (((size_t)tap * NCIC + cic) * (COUT / 16)
                              + (cob >> 4)) * 512 + lane * 8;
        short8b bb[4];
#pragma unroll
        for (int nt = 0; nt < 4; ++nt)
          bb[nt] = *reinterpret_cast<const short8b*>(wt + nt * 512);
#pragma unroll
        for (int mt = 0; mt < 4; ++mt)
#pragma unroll
          for (int nt = 0; nt < 4; ++nt)
            acc[mt][nt] = __builtin_amdgcn_mfma_f32_16x16x32_bf16(a[mt], bb[nt], acc[mt][nt], 0, 0, 0);
      }
    }
  }

#pragma unroll
  for (int mt = 0; mt < 4; ++mt)
#pragma unroll
    for (int nt = 0; nt < 4; ++nt) {
      int co = cob + nt * 16 + m;
      size_t idx = ((size_t)(b * COUT + co)) * HWN + h * 64 + mt * 16 + kg * 4;
      if (BF16OUT) {
        u16* op = (u16*)outv + (size_t)(br * SPLIT + s) * OUTEL + idx;
        ushort4 o;
        o.x = f2bf(acc[mt][nt][0]); o.y = f2bf(acc[mt][nt][1]);
        o.z = f2bf(acc[mt][nt][2]); o.w = f2bf(acc[mt][nt][3]);
        *reinterpret_cast<ushort4*>(op) = o;
      } else {
        float* op = (float*)outv + (size_t)(br * SPLIT + s) * OUTEL + idx;
        *reinterpret_cast<fx4*>(op) = acc[mt][nt];
      }
    }
}

// ---------------- slab reductions ----------------
__global__ __launch_bounds__(256) void breduce_k(const u16* __restrict__ slab,
    float* __restrict__ X) {   // per branch: 2 bf16 slabs of 2*256*4096
  const int br = blockIdx.x >> 10;
  const size_t el = (size_t)2 * DCH * HWN;
  const u16* sb = slab + (size_t)br * 2 * el;
  float* Xb = X + (size_t)br * el;
  const size_t i0 = ((size_t)(blockIdx.x & 1023) * 256 + threadIdx.x) * 8;
  u16x8 s0 = *reinterpret_cast<const u16x8*>(sb + i0);
  u16x8 s1 = *reinterpret_cast<const u16x8*>(sb + el + i0);
  fx4 o0, o1;
#pragma unroll
  for (int j = 0; j < 4; ++j) o0[j] = bf2f(s0[j]) + bf2f(s1[j]);
#pragma unroll
  for (int j = 0; j < 4; ++j) o1[j] = bf2f(s0[4 + j]) + bf2f(s1[4 + j]);
  *reinterpret_cast<fx4*>(Xb + i0) = o0;
  *reinterpret_cast<fx4*>(Xb + i0 + 4) = o1;
}

__global__ __launch_bounds__(256) void sreduce_k(const float* __restrict__ slab,
    float* __restrict__ dout) {  // 4 f32 slabs of 2*512*4096
  const size_t i0 = ((size_t)blockIdx.x * 256 + threadIdx.x) * 4;
  const size_t el = (size_t)2 * 512 * HWN;
  fx4 a = *reinterpret_cast<const fx4*>(slab + i0);
  fx4 b2 = *reinterpret_cast<const fx4*>(slab + el + i0);
  fx4 c2 = *reinterpret_cast<const fx4*>(slab + 2 * el + i0);
  fx4 d2 = *reinterpret_cast<const fx4*>(slab + 3 * el + i0);
#pragma unroll
  for (int j = 0; j < 4; ++j) a[j] = (a[j] + b2[j]) + (c2[j] + d2[j]);
  *reinterpret_cast<fx4*>(dout + i0) = a;
}

// ---------------- batched AB + Ck precompute (all 3 branches) ----------------
__global__ __launch_bounds__(256) void prep3_k(
    const float* __restrict__ sc0, const float* __restrict__ sc1, const float* __restrict__ sc2,
    const float* __restrict__ cw0, const float* __restrict__ cw1, const float* __restrict__ cw2,
    float2* __restrict__ AB, float* __restrict__ Ck) {
  const int br = blockIdx.y;
  const int K = 8 << br;
  const int k = blockIdx.x;
  if (k >= K) return;
  const float* sc = (br == 0) ? sc0 : ((br == 1) ? sc1 : sc2);
  const float* cw = (br == 0) ? cw0 : ((br == 1) ? cw1 : cw2);
  float2* ABb = AB + 2048 * ((1 << br) - 1);
  float* Ckb = Ck + 8 * ((1 << br) - 1);
  const int d = threadIdx.x;
  float s = sc[d * K + k];
  float a = s * s;
  float c = cw[k * DCH + d];
  ABb[d * K + k] = make_float2(a, c * a);
  float tt = c * s;
  tt = tt * tt;
  __shared__ float red[4];
  for (int off = 32; off; off >>= 1) tt += __shfl_down(tt, off);
  int lane = threadIdx.x & 63, wid = threadIdx.x >> 6;
  if (lane == 0) red[wid] = tt;
  __syncthreads();
  if (threadIdx.x == 0) Ckb[k] = red[0] + red[1] + red[2] + red[3];
}

// ---------------- scores + softmax -> Qt, Qsp partials ----------------
template<int K>
__global__ __launch_bounds__(256) void score_k(const float* __restrict__ X,
    const float2* __restrict__ AB, const float* __restrict__ Ck,
    float* __restrict__ Qt, float* __restrict__ Qsp) {
  __shared__ float sm[4 * 64 * (K + 1)];
  const int b = blockIdx.y;
  const int lane = threadIdx.x & 63;
  const int g = threadIdx.x >> 6;
  const int n = blockIdx.x * 64 + lane;
  const float* xp = X + ((size_t)b * DCH) * HWN + n;
  float s_[K];
#pragma unroll
  for (int k = 0; k < K; ++k) s_[k] = 0.f;
  for (int d = g * 64; d < g * 64 + 64; ++d) {
    float xv = xp[(size_t)d * HWN];
    float x2 = xv * xv;
    float xm = -2.f * xv;
    const float2* abp = AB + d * K;
#pragma unroll
    for (int k = 0; k < K; ++k) {
      float2 ab = abp[k];
      s_[k] = fmaf(x2, ab.x, s_[k]);
      s_[k] = fmaf(xm, ab.y, s_[k]);
    }
  }
  float* smr = sm + (g * 64 + lane) * (K + 1);
#pragma unroll
  for (int k = 0; k < K; ++k) smr[k] = s_[k];
  __syncthreads();
  if (g == 0) {
    const float* r0 = sm + lane * (K + 1);
    const float* r1 = sm + (64 + lane) * (K + 1);
    const float* r2 = sm + (128 + lane) * (K + 1);
    const float* r3 = sm + (192 + lane) * (K + 1);
    float mx = -1e30f;
#pragma unroll
    for (int k = 0; k < K; ++k) {
      float v = (r0[k] + r1[k]) + (r2[k] + r3[k]);
      s_[k] = -0.5f * (v + Ck[k]);
      mx = fmaxf(mx, s_[k]);
    }
    float sum = 0.f;
#pragma unroll
    for (int k = 0; k < K; ++k) { float e = expf(s_[k] - mx); s_[k] = e; sum += e; }
    float inv = 1.f / sum;
#pragma unroll
    for (int k = 0; k < K; ++k) {
      float v = s_[k] * inv;
      Qt[((size_t)(b * K + k)) * HWN + n] = v;
      for (int off = 32; off; off >>= 1) v += __shfl_down(v, off);
      if (lane == 0) Qsp[((size_t)(b * K + k)) * 64 + blockIdx.x] = v;
    }
  }
}

// ---------------- Mp[b][d][k][nch] partials over 512-n chunks ----------------
template<int K>
__global__ __launch_bounds__(256) void mmulp_k(const float* __restrict__ X,
    const float* __restrict__ Qt, float* __restrict__ Mp) {
  __shared__ float xs[512];
  __shared__ float pw[4][K + 1];
  const int d = blockIdx.x, nch = blockIdx.y, b = blockIdx.z;
  const int t = threadIdx.x;
  const float* xp = X + ((size_t)(b * DCH + d)) * HWN + nch * 512;
  xs[t] = xp[t]; xs[t + 256] = xp[t + 256];
  __syncthreads();
  const int lane = t & 63, wid = t >> 6;
#pragma unroll
  for (int k = 0; k < K; ++k) {
    const float* qp = Qt + ((size_t)(b * K + k)) * HWN + nch * 512;
    float s = fmaf(xs[t], qp[t], xs[t + 256] * qp[t + 256]);
    for (int off = 32; off; off >>= 1) s += __shfl_down(s, off);
    if (lane == 0) pw[wid][k] = s;
  }
  __syncthreads();
  if (t < K)
    Mp[(((size_t)(b * DCH + d)) * K + t) * 8 + nch] =
        (pw[0][t] + pw[1][t]) + (pw[2][t] + pw[3][t]);
}

// ---------------- fuse1: Qsp/Mp reduce + Z + L2norm + adj + support + relu ------------
template<int K>
__global__ __launch_bounds__(256) void fuse1_k(const float* __restrict__ Mp,
    const float* __restrict__ Qsp, const float* __restrict__ sc,
    const float* __restrict__ cw, const float* __restrict__ Wm,
    float* __restrict__ Graw) {
  __shared__ float zl[DCH * K];
  __shared__ float adj[K * K];
  __shared__ float rn[K];
  __shared__ float qsl[K];
  const int b = blockIdx.x, t = threadIdx.x;
  if (t < K) {
    const float* qp = Qsp + ((size_t)(b * K + t)) * 64;
    float s = 0.f;
    for (int i = 0; i < 64; ++i) s += qp[i];
    qsl[t] = s;
  }
  __syncthreads();
#pragma unroll
  for (int k = 0; k < K; ++k) {
    const float* mp = Mp + (((size_t)(b * DCH + t)) * K + k) * 8;
    fx4 p0 = *reinterpret_cast<const fx4*>(mp);
    fx4 p1 = *reinterpret_cast<const fx4*>(mp + 4);
    float mm = ((p0[0] + p0[1]) + (p0[2] + p0[3])) + ((p1[0] + p1[1]) + (p1[2] + p1[3]));
    float qs = qsl[k];
    zl[t * K + k] = sc[t * K + k] * (mm - cw[k * DCH + t] * qs) / qs;
  }
  __syncthreads();
  if (t < K) {
    float s = 0.f;
    for (int i = 0; i < DCH; ++i) { float v = zl[i * K + t]; s = fmaf(v, v, s); }
    rn[t] = 1.f / sqrtf(s);
  }
  __syncthreads();
#pragma unroll
  for (int k = 0; k < K; ++k) zl[t * K + k] *= rn[k];
  __syncthreads();
  for (int p = t; p < K * K; p += 256) {
    int k = p / K, l = p % K;
    float s = 0.f;
    for (int i = 0; i < DCH; ++i) s = fmaf(zl[i * K + k], zl[i * K + l], s);
    adj[p] = s;
  }
  __syncthreads();
  float sup[K];
#pragma unroll
  for (int k = 0; k < K; ++k) sup[k] = 0.f;
  const float* wr = Wm + (size_t)t * DCH;
  for (int jj = 0; jj < DCH; ++jj) {
    float wv = wr[jj];
#pragma unroll
    for (int k = 0; k < K; ++k) sup[k] = fmaf(wv, zl[jj * K + k], sup[k]);
  }
#pragma unroll
  for (int l = 0; l < K; ++l) {
    float s = 0.f;
#pragma unroll
    for (int k = 0; k < K; ++k) s = fmaf(sup[k], adj[k * K + l], s);
    Graw[((size_t)(b * DCH + t)) * K + l] = fmaxf(s, 0.f);
  }
}

// ---------------- fuse2: BN1d (redundant per block) + EG ----------------
template<int K>
__global__ __launch_bounds__(256) void fuse2_k(const float* __restrict__ Graw,
    const float* __restrict__ gamma, const float* __restrict__ beta,
    const float* __restrict__ E, float* __restrict__ EG) {
  __shared__ float gl[DCH * K];
  __shared__ float er[128 * 2 * (K + 1)];
  const int b = blockIdx.x, ob = blockIdx.y, t = threadIdx.x;
  {
    const int d = t;
    float s = 0.f, ss = 0.f;
#pragma unroll
    for (int b2 = 0; b2 < 2; ++b2)
#pragma unroll
      for (int l = 0; l < K; ++l) {
        float v = Graw[((size_t)(b2 * DCH + d)) * K + l];
        s += v; ss = fmaf(v, v, ss);
      }
    const float invn = 1.f / (2 * K);
    float mean = s * invn;
    float var  = ss * invn - mean * mean;
    float giv  = gamma[d] / sqrtf(var + EPSV);
    float be   = beta[d];
#pragma unroll
    for (int l = 0; l < K; ++l) {
      float v = Graw[((size_t)(b * DCH + d)) * K + l];
      gl[d * K + l] = fmaf(v - mean, giv, be);
    }
  }
  __syncthreads();
  const int o = ob * 128 + (t >> 1);
  const int half = t & 1;
  float a[K];
#pragma unroll
  for (int k = 0; k < K; ++k) a[k] = 0.f;
  const fx4* e4 = reinterpret_cast<const fx4*>(E + (size_t)o * DCH + half * 128);
  for (int d4 = 0; d4 < 32; ++d4) {
    fx4 v = e4[d4];
#pragma unroll
    for (int j = 0; j < 4; ++j) {
      float vv = v[j];
#pragma unroll
      for (int k = 0; k < K; ++k)
        a[k] = fmaf(vv, gl[(half * 128 + d4 * 4 + j) * K + k], a[k]);
    }
  }
  float* erow = er + (size_t)(t >> 1) * (2 * (K + 1)) + half * (K + 1);
#pragma unroll
  for (int k = 0; k < K; ++k) erow[k] = a[k];
  __syncthreads();
  if (half == 0) {
    const float* e2 = er + (size_t)(t >> 1) * (2 * (K + 1));
#pragma unroll
    for (int k = 0; k < K; ++k)
      EG[((size_t)(b * 512 + o)) * K + k] = e2[k] + e2[K + 1 + k];
  }
}

// ---------------- Y = EG @ Qt + c -> CHWc bf16 cat (512 blocks) ----------------
template<int K>
__global__ __launch_bounds__(256) void yout_chwc_k(const float* __restrict__ EG,
    const float* __restrict__ Qt, const float* __restrict__ cres,
    u16* __restrict__ cat, int coff) {
  __shared__ u16 egl[K * 128];
  const int b = blockIdx.z, cg = blockIdx.y;
  const int t = threadIdx.x;
  const int lane = t & 63, sub = t >> 6;
  const int n = blockIdx.x * 64 + lane;
  for (int i = t; i < K * 128; i += 256) {
    int k = i >> 7, co = i & 127;
    egl[i] = f2bf(EG[((size_t)(b * 512 + cg * 128 + co)) * K + k]);
  }
  float q[K];
#pragma unroll
  for (int k = 0; k < K; ++k) q[k] = Qt[((size_t)(b * K + k)) * HWN + n];
  __syncthreads();
  const float* crow = cres + (size_t)b * 512 * HWN + n;
#pragma unroll
  for (int it = 0; it < 4; ++it) {
    int co = sub * 32 + it * 8;
    int gco = cg * 128 + co;
    float y[8];
#pragma unroll
    for (int jj = 0; jj < 8; ++jj) y[jj] = crow[(size_t)(gco + jj) * HWN];
#pragma unroll
    for (int k = 0; k < K; ++k) {
      u16x8 eg = *reinterpret_cast<const u16x8*>(&egl[k * 128 + co]);
#pragma unroll
      for (int jj = 0; jj < 8; ++jj) y[jj] = fmaf(bf2f(eg[jj]), q[k], y[jj]);
    }
    u16x8 o;
#pragma unroll
    for (int jj = 0; jj < 8; ++jj) o[jj] = f2bf(y[jj]);
    int ch = coff + gco;
    *reinterpret_cast<u16x8*>(cat +
        (((size_t)(b * 48 + (ch >> 5)) * HWN + n) * 32 + (ch & 31))) = o;
  }
}

// ---------------- smooth BN stats + relu ----------------
__global__ __launch_bounds__(256) void bnstat_k(const float* __restrict__ out,
    float* __restrict__ stat) {
  const int o = blockIdx.x;
  float s = 0.f, ss = 0.f;
  for (int i = threadIdx.x; i < 2 * HWN; i += 256) {
    int b = i >> 12, n = i & (HWN - 1);
    float v = out[((size_t)(b * 512 + o)) * HWN + n];
    s += v; ss = fmaf(v, v, ss);
  }
  __shared__ float rs[4], rss[4];
  for (int off = 32; off; off >>= 1) { s += __shfl_down(s, off); ss += __shfl_down(ss, off); }
  int lane = threadIdx.x & 63, wid = threadIdx.x >> 6;
  if (lane == 0) { rs[wid] = s; rss[wid] = ss; }
  __syncthreads();
  if (threadIdx.x == 0) {
    float S = rs[0] + rs[1] + rs[2] + rs[3];
    float SS = rss[0] + rss[1] + rss[2] + rss[3];
    float mean = S / (2 * HWN);
    float var  = SS / (2 * HWN) - mean * mean;
    stat[o] = mean;
    stat[512 + o] = 1.f / sqrtf(var + EPSV);
  }
}

__global__ __launch_bounds__(256) void bnrelu_k(float* __restrict__ out,
    const float* __restrict__ stat, const float* __restrict__ g,
    const float* __restrict__ bb) {
  int idx = blockIdx.x * 256 + threadIdx.x;
  int o = (idx >> 12) & 511;
  float v = out[idx];
  float r = fmaf((v - stat[o]) * stat[512 + o], g[o], bb[o]);
  out[idx] = fmaxf(r, 0.f);
}

extern "C" void kernel_launch(void* const* d_in, const int* in_sizes, int n_in,
                              void* d_out, int out_size, void* d_ws, size_t ws_size,
                              hipStream_t stream) {
  const float* c3 = (const float*)d_in[0];
  const float* c4 = (const float*)d_in[1];
  const float* c5 = (const float*)d_in[2];
  const float* smooth_w = (const float*)d_in[24];
  const float* smg = (const float*)d_in[25];
  const float* smb = (const float*)d_in[26];
  float* dout = (float*)d_out;

  char* wsb = (char*)d_ws;
  // A: Xt3 (phase1) then cat (phase2/3)
  u16* Xt3 = (u16*)wsb;
  u16* cat = (u16*)wsb;                          // 25,165,824 B
  u16* Wb  = (u16*)(wsb + 25165824);             // 14,155,776 B (branch packs / smooth pack)
  float* stat = (float*)(wsb + 39321600);        // 4 KB
  float* pool = (float*)(wsb + 39325696);        // 4 MB small pool (dead by phase3)
  // C region @43,520,000: phase1/2 {bslab 25.2M | X3 25.2M}; phase3 {sslab 67.1M}
  u16* bslab   = (u16*)(wsb + 43520000);
  float* X3    = (float*)(wsb + 68685824);
  float* sslab = (float*)(wsb + 43520000);

  // pool layout (floats)
  float* Qt3  = pool;            // {0, 65536, 196608} tot 458752
  float* Qsp3 = pool + 458752;   // {0, 1024, 3072} tot 7168
  float* Mp3  = pool + 465920;   // {0, 32768, 98304} tot 229376
  float* Graw3 = pool + 723968;  // {0, 4096, 12288} tot 28672
  float* EG3  = pool + 752640;   // {0, 8192, 24576} tot 57344
  float2* AB3 = (float2*)(pool + 809984);  // {0,2048,6144} float2, tot 14336
  float* Ck3  = pool + 838656;   // {0,8,24} tot 56

  // branch br: K = 8<<br; br0=c5/K8 (din 17..23), br1=c4/K16 (10..16), br2=c3/K32 (3..9)
  const float* cin_[3] = {c5, c4, c3};
  const int dbase[3] = {17, 10, 3};
  const int coff_[3] = {0, 512, 1024};
  const size_t XEL = (size_t)2 * DCH * HWN;

  // ---- phase 1: batched branch convs
  t_chwc3_k<<<dim3(16, 16, 6), 256, 0, stream>>>(c5, c4, c3, Xt3);
  wpack_k<512, 256><<<dim3(256, 3), 256, 0, stream>>>(
      (const float*)d_in[17], (const float*)d_in[10], (const float*)d_in[3], Wb);
  convsp_k<512, 256, 2, true><<<dim3(256, 3), 256, 0, stream>>>(Xt3, Wb, bslab);
  breduce_k<<<3072, 256, 0, stream>>>(bslab, X3);

  // ---- phase 2
  prep3_k<<<dim3(32, 3), 256, 0, stream>>>(
      (const float*)d_in[19], (const float*)d_in[12], (const float*)d_in[5],
      (const float*)d_in[18], (const float*)d_in[11], (const float*)d_in[4],
      AB3, Ck3);
  score_k<8><<<dim3(64, 2), 256, 0, stream>>>(X3, AB3, Ck3, Qt3, Qsp3);
  score_k<16><<<dim3(64, 2), 256, 0, stream>>>(X3 + XEL, AB3 + 2048, Ck3 + 8,
                                               Qt3 + 65536, Qsp3 + 1024);
  score_k<32><<<dim3(64, 2), 256, 0, stream>>>(X3 + 2 * XEL, AB3 + 6144, Ck3 + 24,
                                               Qt3 + 196608, Qsp3 + 3072);
  mmulp_k<8><<<dim3(256, 8, 2), 256, 0, stream>>>(X3, Qt3, Mp3);
  mmulp_k<16><<<dim3(256, 8, 2), 256, 0, stream>>>(X3 + XEL, Qt3 + 65536, Mp3 + 32768);
  mmulp_k<32><<<dim3(256, 8, 2), 256, 0, stream>>>(X3 + 2 * XEL, Qt3 + 196608, Mp3 + 98304);
  fuse1_k<8><<<2, 256, 0, stream>>>(Mp3, Qsp3, (const float*)d_in[19],
      (const float*)d_in[18], (const float*)d_in[20], Graw3);
  fuse1_k<16><<<2, 256, 0, stream>>>(Mp3 + 32768, Qsp3 + 1024, (const float*)d_in[12],
      (const float*)d_in[11], (const float*)d_in[13], Graw3 + 4096);
  fuse1_k<32><<<2, 256, 0, stream>>>(Mp3 + 98304, Qsp3 + 3072, (const float*)d_in[5],
      (const float*)d_in[4], (const float*)d_in[6], Graw3 + 12288);
  fuse2_k<8><<<dim3(2, 4), 256, 0, stream>>>(Graw3, (const float*)d_in[21],
      (const float*)d_in[22], (const float*)d_in[23], EG3);
  fuse2_k<16><<<dim3(2, 4), 256, 0, stream>>>(Graw3 + 4096, (const float*)d_in[14],
      (const float*)d_in[15], (const float*)d_in[16], EG3 + 8192);
  fuse2_k<32><<<dim3(2, 4), 256, 0, stream>>>(Graw3 + 12288, (const float*)d_in[7],
      (const float*)d_in[8], (const float*)d_in[9], EG3 + 24576);
  yout_chwc_k<8><<<dim3(64, 4, 2), 256, 0, stream>>>(EG3, Qt3, c5, cat, 0);
  yout_chwc_k<16><<<dim3(64, 4, 2), 256, 0, stream>>>(EG3 + 8192, Qt3 + 65536, c4, cat, 512);
  yout_chwc_k<32><<<dim3(64, 4, 2), 256, 0, stream>>>(EG3 + 24576, Qt3 + 196608, c3, cat, 1024);

  // ---- phase 3: smooth conv + BN2d + relu
  wpack_k<1536, 512><<<dim3(1536, 1), 256, 0, stream>>>(smooth_w, smooth_w, smooth_w, Wb);
  convsp_k<1536, 512, 4, false><<<dim3(1024, 1), 256, 0, stream>>>(cat, Wb, sslab);
  sreduce_k<<<4096, 256, 0, stream>>>(sslab, dout);
  bnstat_k<<<512, 256, 0, stream>>>(dout, stat);
  bnrelu_k<<<16384, 256, 0, stream>>>(dout, stat, smg, smb);
}